// Round 5
// baseline (218.818 us; speedup 1.0000x reference)
//
#include <hip/hip_runtime.h>

typedef __bf16 bf16x8 __attribute__((ext_vector_type(8)));
typedef float f32x4 __attribute__((ext_vector_type(4)));
typedef unsigned short u16;

__device__ __forceinline__ u16 f2b(float f) {
  unsigned u = __builtin_bit_cast(unsigned, f);
  u = (u + 0x7FFFu + ((u >> 16) & 1u)) >> 16;
  return (u16)u;
}
__device__ __forceinline__ float b2f(u16 h) {
  return __builtin_bit_cast(float, (unsigned)h << 16);
}

// async global->LDS, 16B per lane. dst = wave-uniform base + lane*16.
__device__ __forceinline__ void glds16(const u16* g, u16* l) {
  __builtin_amdgcn_global_load_lds(
      (const __attribute__((address_space(1))) unsigned*)g,
      (__attribute__((address_space(3))) unsigned*)l, 16, 0, 0);
}

// ---------------------------------------------------------------------------
// Swizzled layouts (16B = 8-u16 units, BK=32 K-tiles):
// X [24576,256]: q -> b=q/48, m=q%48; c -> kt=c>>5, g=(c>>3)&3, j=c&7;
//   u = m*4 + (g ^ ((m>>1)&3));  elem off = b*12288 + kt*1536 + u*8 + j
// W [256,K]: n,c -> kt=c>>5, g=(c>>3)&3, j=c&7; u = n*4 + (g^((n>>1)&3));
//   off = kt*8192 + u*8 + j
// H (LDS, 48x256): m,k -> g=k>>3 in [0,32); u = m*32 + (g ^ ((m>>1)&7))
// All give 8 banks x 2-way (free) on 16-lane fragment reads.
// ---------------------------------------------------------------------------

// ---------------------------------------------------------------------------
// Column decode table: col -> (src scalar idx, freq, kind)
// kind: 0 raw, 1 sin, 2 cos, 3 zero.  enc = src | f<<5 | kind<<9
// ---------------------------------------------------------------------------
struct FT {
  u16 v[256];
  static constexpr u16 enc(int s, int f, int k) {
    return (u16)(s | (f << 5) | (k << 9));
  }
  constexpr void p3(int base, int F, int src) {
    v[base + 0] = enc(src + 0, 0, 0);
    v[base + 1] = enc(src + 1, 0, 0);
    v[base + 2] = enc(src + 2, 0, 0);
    for (int f = 0; f < F; ++f)
      for (int r = 0; r < 6; ++r) {
        int comp = (r < 3) ? r : r - 3;
        v[base + 3 + f * 6 + r] = enc(src + comp, f, (r < 3) ? 1 : 2);
      }
  }
  constexpr void p1(int base, int F, int src) {
    v[base] = enc(src, 0, 0);
    for (int f = 0; f < F; ++f) {
      v[base + 1 + 2 * f] = enc(src, f, 1);
      v[base + 2 + 2 * f] = enc(src, f, 2);
    }
  }
  constexpr FT() : v{} {
    p3(0, 10, 0);     // hit_pos_emb   (q)          [0..62]
    p1(63, 4, 3);     // density_emb                [63..71]
    p3(72, 10, 4);    // smoothed_emb  (sp)         [72..134]
    p3(135, 10, 7);   // var_emb       (var)        [135..197]
    p3(198, 4, 10);   // hit_dir_emb   (ray dir)    [198..224]
    p3(225, 4, 13);   // dirs_emb      (dir)        [225..251]
    v[252] = enc(16, 0, 0);  // normals
    v[253] = enc(17, 0, 0);
    v[254] = enc(18, 0, 0);
    v[255] = enc(0, 0, 3);   // pad col
  }
};
__constant__ FT ftab = FT();

// ---------------------------------------------------------------------------
// Kernel 1: weight prep fp32 -> split bf16 planes, BK=32 swizzled layout.
// W0 [256,511] -> [256,512]: col 255 = 0, cols 256..511 = orig 255..510.
// ---------------------------------------------------------------------------
__global__ __launch_bounds__(256) void prep_weights(
    const float* __restrict__ W0, const float* __restrict__ W1,
    const float* __restrict__ W2,
    u16* __restrict__ w0h, u16* __restrict__ w0l,
    u16* __restrict__ w1h, u16* __restrict__ w1l,
    u16* __restrict__ w2h, u16* __restrict__ w2l)
{
  int i = blockIdx.x * 256 + threadIdx.x;   // 0 .. 262143
  float v; u16 *ph, *pl; int n, c;
  if (i < 131072) {
    n = i >> 9; c = i & 511;
    v = (c < 255) ? W0[n * 511 + c] : ((c == 255) ? 0.0f : W0[n * 511 + (c - 1)]);
    ph = w0h; pl = w0l;
  } else if (i < 196608) {
    int j = i - 131072; n = j >> 8; c = j & 255; v = W1[j]; ph = w1h; pl = w1l;
  } else {
    int j = i - 196608; n = j >> 8; c = j & 255; v = W2[j]; ph = w2h; pl = w2l;
  }
  int kt = c >> 5, g = (c >> 3) & 3, jj = c & 7;
  int u = n * 4 + (g ^ ((n >> 1) & 3));
  int off = kt * 8192 + u * 8 + jj;
  u16 h = f2b(v);
  ph[off] = h;
  pl[off] = f2b(v - b2f(h));
}

// ---------------------------------------------------------------------------
// Kernel 2: build 10x10x10 cell grid over the 4096 particles.
// Outputs: cell-sorted SoA (spx,spy,spz), orig index per slot, cellStart[1001].
// ---------------------------------------------------------------------------
__global__ __launch_bounds__(1024) void grid_build(
    const float* __restrict__ parts,
    float* __restrict__ spx, float* __restrict__ spy, float* __restrict__ spz,
    u16* __restrict__ sidx, u16* __restrict__ cellStart)
{
  __shared__ int cnt[1000];
  __shared__ int wsum[16];
  const int t = threadIdx.x;
  const int lane = t & 63, wv = t >> 6;
  if (t < 1000) cnt[t] = 0;
  __syncthreads();
  int cid[4]; float ppx[4], ppy[4], ppz[4];
  #pragma unroll
  for (int s = 0; s < 4; ++s) {
    int j = t + s * 1024;
    float x = parts[3 * j], y = parts[3 * j + 1], z = parts[3 * j + 2];
    int cx = (int)(x * 10.f); cx = cx > 9 ? 9 : cx;
    int cy = (int)(y * 10.f); cy = cy > 9 ? 9 : cy;
    int cz = (int)(z * 10.f); cz = cz > 9 ? 9 : cz;
    cid[s] = (cz * 10 + cy) * 10 + cx;
    ppx[s] = x; ppy[s] = y; ppz[s] = z;
    atomicAdd(&cnt[cid[s]], 1);
  }
  __syncthreads();
  int v = (t < 1000) ? cnt[t] : 0;
  int inc = v;
  #pragma unroll
  for (int o = 1; o < 64; o <<= 1) {
    int u = __shfl_up(inc, o, 64);
    if (lane >= o) inc += u;
  }
  if (lane == 63) wsum[wv] = inc;
  __syncthreads();
  if (wv == 0 && lane < 16) {
    int w = wsum[lane];
    #pragma unroll
    for (int o = 1; o < 16; o <<= 1) {
      int u = __shfl_up(w, o, 64);
      if (lane >= o) w += u;
    }
    wsum[lane] = w;
  }
  __syncthreads();
  int excl = inc - v + (wv ? wsum[wv - 1] : 0);
  if (t < 1000) cellStart[t] = (u16)excl;
  if (t == 0) cellStart[1000] = (u16)4096;
  __syncthreads();
  if (t < 1000) cnt[t] = excl;
  __syncthreads();
  #pragma unroll
  for (int s = 0; s < 4; ++s) {
    int pos = atomicAdd(&cnt[cid[s]], 1);
    spx[pos] = ppx[s]; spy[pos] = ppy[s]; spz[pos] = ppz[s];
    sidx[pos] = (u16)(t + s * 1024);
  }
}

// ---------------------------------------------------------------------------
// Kernel 3: per-LANE ball query via grid; first-16-by-index via sorted
// insertion on packed keys (origIdx<<12 | slot). Writes 20-f32 stats/query.
// ---------------------------------------------------------------------------
__global__ __launch_bounds__(256) void query_kernel(
    const float* __restrict__ points, const float* __restrict__ normals,
    const float* __restrict__ rays, const float* __restrict__ ro,
    const float* __restrict__ gpx, const float* __restrict__ gpy,
    const float* __restrict__ gpz, const u16* __restrict__ sidx,
    const u16* __restrict__ cellStart, float* __restrict__ stats)
{
  __shared__ float lpx[4096], lpy[4096], lpz[4096];
  __shared__ u16 lsi[4096];
  __shared__ u16 lcs[1008];
  const int t = threadIdx.x;
  for (int j = t; j < 4096; j += 256) {
    lpx[j] = gpx[j]; lpy[j] = gpy[j]; lpz[j] = gpz[j]; lsi[j] = sidx[j];
  }
  for (int j = t; j < 1001; j += 256) lcs[j] = cellStart[j];
  __syncthreads();

  const int q = blockIdx.x * 256 + t;
  const float qx = points[3 * q], qy = points[3 * q + 1], qz = points[3 * q + 2];
  const float RQ = 0.1f * 0.1f;
  int cx = (int)(qx * 10.f); cx = cx > 9 ? 9 : cx;
  int cy = (int)(qy * 10.f); cy = cy > 9 ? 9 : cy;
  int cz = (int)(qz * 10.f); cz = cz > 9 ? 9 : cz;

  unsigned lst[16];
  #pragma unroll
  for (int k = 0; k < 16; ++k) lst[k] = 0xFFFFFFFFu;

  const int zlo = cz > 0 ? cz - 1 : 0, zhi = cz < 9 ? cz + 1 : 9;
  const int ylo = cy > 0 ? cy - 1 : 0, yhi = cy < 9 ? cy + 1 : 9;
  const int xlo = cx > 0 ? cx - 1 : 0, xhi = cx < 9 ? cx + 1 : 9;
  for (int z = zlo; z <= zhi; ++z)
    for (int y = ylo; y <= yhi; ++y) {
      int rowc = (z * 10 + y) * 10;
      int p0 = lcs[rowc + xlo], p1 = lcs[rowc + xhi + 1];  // x-run contiguous
      for (int p = p0; p < p1; ++p) {
        float ex = lpx[p] - qx, ey = lpy[p] - qy, ez = lpz[p] - qz;
        float d2 = __fadd_rn(__fadd_rn(__fmul_rn(ex, ex), __fmul_rn(ey, ey)), __fmul_rn(ez, ez));
        if (d2 < RQ) {
          unsigned key = ((unsigned)lsi[p] << 12) | (unsigned)p;
          if (key < lst[15]) {
            #pragma unroll
            for (int k = 0; k < 16; ++k) {
              unsigned cur = lst[k];
              bool lt = key < cur;
              lst[k] = lt ? key : cur;
              key = lt ? cur : key;
            }
          }
        }
      }
    }

  // accumulate stats in ascending original-index order
  int n = 0;
  float sdx = 0, sdy = 0, sdz = 0, s2x = 0, s2y = 0, s2z = 0;
  float sw = 0, swx = 0, swy = 0, swz = 0;
  #pragma unroll
  for (int k = 0; k < 16; ++k) {
    unsigned e = lst[k];
    if (e != 0xFFFFFFFFu) {
      int p = e & 0xFFF;
      float px = lpx[p], py = lpy[p], pz = lpz[p];
      float ex = px - qx, ey = py - qy, ez = pz - qz;
      n++;
      sdx += ex; sdy += ey; sdz += ez;
      s2x += ex * ex; s2y += ey * ey; s2z += ez * ez;
      float d2 = ex * ex + ey * ey + ez * ez;
      float dn = sqrtf(d2);
      float tt = dn * 10.0f;
      float w = fmaxf(1.0f - tt * tt * tt, 0.0f);
      sw += w; swx += w * px; swy += w * py; swz += w * pz;
    }
  }

  float fn = (float)n;
  float tq = sqrtf(qx * qx + qy * qy + qz * qz) * 10.0f;
  float wpad = fmaxf(1.0f - tq * tq * tq, 0.0f);
  float density = sw + (16.0f - fn) * wpad;
  float invd = 1.0f / (density + 1e-12f);
  float spx_ = swx * invd, spy_ = swy * invd, spz_ = swz * invd;

  float invn = 1.0f / (fn + 1e-12f);
  float mx = sdx * invn, my = sdy * invn, mz = sdz * invn;
  float vx = fmaxf((s2x - 2.0f * mx * sdx + fn * mx * mx) * invn, 0.0f);
  float vy = fmaxf((s2y - 2.0f * my * sdy + fn * my * my) * invn, 0.0f);
  float vz = fmaxf((s2z - 2.0f * mz * sdz + fn * mz * mz) * invn, 0.0f);

  float dxx = spx_ - ro[0], dyy = spy_ - ro[1], dzz = spz_ - ro[2];
  float il = 1.0f / sqrtf(dxx * dxx + dyy * dyy + dzz * dzz);

  float* s = stats + (size_t)q * 20;
  s[0] = qx; s[1] = qy; s[2] = qz; s[3] = density;
  s[4] = spx_; s[5] = spy_; s[6] = spz_;
  s[7] = vx; s[8] = vy; s[9] = vz;
  int r = q / 48;
  s[10] = rays[6 * r + 3]; s[11] = rays[6 * r + 4]; s[12] = rays[6 * r + 5];
  s[13] = dxx * il; s[14] = dyy * il; s[15] = dzz * il;
  s[16] = normals[3 * q]; s[17] = normals[3 * q + 1]; s[18] = normals[3 * q + 2];
  s[19] = 0.0f;
}

// ---------------------------------------------------------------------------
// Kernel 4: posenc from stats -> swizzled X planes [24576,256]. Wave/query.
// ---------------------------------------------------------------------------
__global__ __launch_bounds__(1024) void posenc_kernel(
    const float* __restrict__ stats, u16* __restrict__ Xh, u16* __restrict__ Xl)
{
  const int tid = threadIdx.x, lane = tid & 63, wv = tid >> 6;
  const int q = blockIdx.x * 16 + wv;
  const float* s = stats + (size_t)q * 20;
  const int b = q / 48, m = q % 48;
  const size_t base = (size_t)b * 12288;
  #pragma unroll
  for (int it = 0; it < 4; ++it) {
    int c = it * 64 + lane;
    int e = ftab.v[c];
    float sv = s[e & 31];
    float arg = sv * (float)(1 << ((e >> 5) & 15));
    float sn, cs;
    sincosf(arg, &sn, &cs);
    int kind = e >> 9;
    float val = (kind == 0) ? sv : (kind == 1 ? sn : (kind == 2 ? cs : 0.0f));
    u16 h = f2b(val);
    int kt = c >> 5, g = (c >> 3) & 3, j = c & 7;
    int u = m * 4 + (g ^ ((m >> 1) & 3));
    size_t off = base + kt * 1536 + u * 8 + j;
    Xh[off] = h;
    Xl[off] = f2b(val - b2f(h));
  }
}

// ---------------------------------------------------------------------------
// Kernel 5: fused 3-layer split-bf16 MFMA MLP + final 256->3 + sigmoid.
// 512 blocks x 256 thr (4 waves, wave tile 48x64), 48 rows/block, 80 KB LDS
// -> 2 blocks/CU (two independent barrier domains).
// LDS: Hh [0,24576) Hl [24576,49152) | Bsh [49152,65536) Bsl [65536,81920)
// L0 A-stage aliases H[0,6144); w3s aliases Bsh in final phase.
// acc += Ah*Bh + Ah*Bl + Al*Bh per fragment pair.
// ---------------------------------------------------------------------------
__global__ __launch_bounds__(256) void fused_mlp(
    const u16* __restrict__ Xh, const u16* __restrict__ Xl,
    const float* __restrict__ fvec,
    const u16* __restrict__ w0h, const u16* __restrict__ w0l,
    const u16* __restrict__ w1h, const u16* __restrict__ w1l,
    const u16* __restrict__ w2h, const u16* __restrict__ w2l,
    const float* __restrict__ b0, const float* __restrict__ b1,
    const float* __restrict__ b2,
    const float* __restrict__ W3, const float* __restrict__ b3,
    float* __restrict__ out)
{
  extern __shared__ char lds[];
  u16* Hh    = (u16*)lds;
  u16* Hl    = (u16*)(lds + 24576);
  u16* Bsh   = (u16*)(lds + 49152);
  u16* Bsl   = (u16*)(lds + 65536);
  u16* Ah_st = (u16*)lds;
  u16* Al_st = (u16*)(lds + 3072);
  float* w3s = (float*)(lds + 49152);

  const int tid = threadIdx.x, lane = tid & 63, wn = tid >> 6;
  const int l15 = lane & 15, l4 = lane >> 4;
  const int blk = blockIdx.x;

  f32x4 acc[3][4];
  #pragma unroll
  for (int i = 0; i < 3; ++i)
    #pragma unroll
    for (int j = 0; j < 4; ++j) acc[i][j] = (f32x4){0, 0, 0, 0};

  const u16* Xht = Xh + (size_t)blk * 12288;
  const u16* Xlt = Xl + (size_t)blk * 12288;

  auto bfrags = [&](bf16x8* bh, bf16x8* bl) {
    #pragma unroll
    for (int j = 0; j < 4; ++j) {
      int n = wn * 64 + j * 16 + l15;
      int u = n * 4 + (l4 ^ ((n >> 1) & 3));
      bh[j] = __builtin_bit_cast(bf16x8, *(const uint4*)(Bsh + u * 8));
      bl[j] = __builtin_bit_cast(bf16x8, *(const uint4*)(Bsl + u * 8));
    }
  };
  auto mfmas = [&](bf16x8* ah, bf16x8* al, bf16x8* bh, bf16x8* bl) {
    #pragma unroll
    for (int i = 0; i < 3; ++i)
      #pragma unroll
      for (int j = 0; j < 4; ++j) {
        acc[i][j] = __builtin_amdgcn_mfma_f32_16x16x32_bf16(ah[i], bh[j], acc[i][j], 0, 0, 0);
        acc[i][j] = __builtin_amdgcn_mfma_f32_16x16x32_bf16(ah[i], bl[j], acc[i][j], 0, 0, 0);
        acc[i][j] = __builtin_amdgcn_mfma_f32_16x16x32_bf16(al[i], bh[j], acc[i][j], 0, 0, 0);
      }
  };
  auto epilogue = [&](const float* bias_) {
    float bv[4];
    #pragma unroll
    for (int j = 0; j < 4; ++j) bv[j] = bias_[wn * 64 + j * 16 + l15];
    #pragma unroll
    for (int i = 0; i < 3; ++i) {
      #pragma unroll
      for (int r = 0; r < 4; ++r) {
        int m = i * 16 + l4 * 4 + r;
        #pragma unroll
        for (int j = 0; j < 4; ++j) {
          int n = wn * 64 + j * 16 + l15;
          float v = fmaxf(acc[i][j][r] + bv[j], 0.0f);
          u16 h = f2b(v);
          int u = m * 32 + ((n >> 3) ^ ((m >> 1) & 7));
          int off = u * 8 + (n & 7);
          Hh[off] = h;
          Hl[off] = f2b(v - b2f(h));
        }
      }
    }
  };

  // ======================= L0: K=512 (8 kt from X, 8 from fvec) ============
  for (int kt = 0; kt < 16; ++kt) {
    if (kt < 8) {
      // A: 6 chunks of 1 KB (3 hi + 3 lo) via glds
      const u16* s0; u16* d0;
      if (wn < 3) { s0 = Xht + kt * 1536 + wn * 512; d0 = Ah_st + wn * 512; }
      else        { s0 = Xlt + kt * 1536;            d0 = Al_st; }
      glds16(s0 + lane * 8, d0 + lane * 8);
      if (wn < 2)
        glds16(Xlt + kt * 1536 + (wn + 1) * 512 + lane * 8,
               Al_st + (wn + 1) * 512 + lane * 8);
    } else {
      // A: fvec fp32, split in registers (threads 0..191 = waves 0..2)
      if (tid < 192) {
        int m = tid >> 2, g = tid & 3;
        const float* src = fvec + (size_t)(blk * 48 + m) * 256 + (kt - 8) * 32 + g * 8;
        float4 v0 = ((const float4*)src)[0];
        float4 v1 = ((const float4*)src)[1];
        float vv[8] = {v0.x, v0.y, v0.z, v0.w, v1.x, v1.y, v1.z, v1.w};
        u16 hs[8], ls[8];
        #pragma unroll
        for (int s = 0; s < 8; ++s) {
          hs[s] = f2b(vv[s]);
          ls[s] = f2b(vv[s] - b2f(hs[s]));
        }
        int u = m * 4 + (g ^ ((m >> 1) & 3));
        *(uint4*)(Ah_st + u * 8) = *(uint4*)hs;
        *(uint4*)(Al_st + u * 8) = *(uint4*)ls;
      }
    }
    // B: 32 chunks of 1 KB
    #pragma unroll
    for (int s = 0; s < 8; ++s) {
      int ch = wn + s * 4;
      const u16* bs = (ch < 16) ? (w0h + kt * 8192 + ch * 512)
                                : (w0l + kt * 8192 + (ch - 16) * 512);
      u16* bd = (ch < 16) ? (Bsh + ch * 512) : (Bsl + (ch - 16) * 512);
      glds16(bs + lane * 8, bd + lane * 8);
    }
    __syncthreads();
    bf16x8 ah[3], al[3], bh[4], bl[4];
    #pragma unroll
    for (int i = 0; i < 3; ++i) {
      int m = i * 16 + l15;
      int u = m * 4 + (l4 ^ ((m >> 1) & 3));
      ah[i] = __builtin_bit_cast(bf16x8, *(const uint4*)(Ah_st + u * 8));
      al[i] = __builtin_bit_cast(bf16x8, *(const uint4*)(Al_st + u * 8));
    }
    bfrags(bh, bl);
    mfmas(ah, al, bh, bl);
    __syncthreads();
  }
  epilogue(b0);
  __syncthreads();

  // ======================= L1, L2: K=256, A from H (in-place) ==============
  #pragma unroll 1
  for (int layer = 0; layer < 2; ++layer) {
    const u16* wh_ = layer ? w2h : w1h;
    const u16* wl_ = layer ? w2l : w1l;
    #pragma unroll
    for (int i = 0; i < 3; ++i)
      #pragma unroll
      for (int j = 0; j < 4; ++j) acc[i][j] = (f32x4){0, 0, 0, 0};

    for (int kt = 0; kt < 8; ++kt) {
      #pragma unroll
      for (int s = 0; s < 8; ++s) {
        int ch = wn + s * 4;
        const u16* bs = (ch < 16) ? (wh_ + kt * 8192 + ch * 512)
                                  : (wl_ + kt * 8192 + (ch - 16) * 512);
        u16* bd = (ch < 16) ? (Bsh + ch * 512) : (Bsl + (ch - 16) * 512);
        glds16(bs + lane * 8, bd + lane * 8);
      }
      __syncthreads();
      bf16x8 ah[3], al[3], bh[4], bl[4];
      #pragma unroll
      for (int i = 0; i < 3; ++i) {
        int m = i * 16 + l15;
        int g = kt * 4 + l4;
        int u = m * 32 + (g ^ ((m >> 1) & 7));
        ah[i] = __builtin_bit_cast(bf16x8, *(const uint4*)(Hh + u * 8));
        al[i] = __builtin_bit_cast(bf16x8, *(const uint4*)(Hl + u * 8));
      }
      bfrags(bh, bl);
      mfmas(ah, al, bh, bl);
      __syncthreads();
    }
    epilogue(layer ? b2 : b1);
    __syncthreads();
  }

  // ======================= final: 256 -> 3 + sigmoid =======================
  for (int i = tid; i < 768; i += 256) w3s[i] = W3[i];
  __syncthreads();

  const float B30 = b3[0], B31 = b3[1], B32 = b3[2];
  #pragma unroll 1
  for (int rr = 0; rr < 12; ++rr) {
    int m = wn * 12 + rr;
    int g = lane >> 1, j0 = (lane & 1) * 4;
    int u = m * 32 + (g ^ ((m >> 1) & 7));
    uint2 ph_ = *(const uint2*)(Hh + u * 8 + j0);
    uint2 pl_ = *(const uint2*)(Hl + u * 8 + j0);
    float h0 = b2f((u16)(ph_.x & 0xffff)) + b2f((u16)(pl_.x & 0xffff));
    float h1 = b2f((u16)(ph_.x >> 16))    + b2f((u16)(pl_.x >> 16));
    float h2 = b2f((u16)(ph_.y & 0xffff)) + b2f((u16)(pl_.y & 0xffff));
    float h3 = b2f((u16)(ph_.y >> 16))    + b2f((u16)(pl_.y >> 16));
    int kc = lane * 4;
    float4 wa = *(const float4*)(w3s + kc);
    float4 wb = *(const float4*)(w3s + 256 + kc);
    float4 wc = *(const float4*)(w3s + 512 + kc);
    float p0 = fmaf(h3, wa.w, fmaf(h2, wa.z, fmaf(h1, wa.y, h0 * wa.x)));
    float p1 = fmaf(h3, wb.w, fmaf(h2, wb.z, fmaf(h1, wb.y, h0 * wb.x)));
    float p2 = fmaf(h3, wc.w, fmaf(h2, wc.z, fmaf(h1, wc.y, h0 * wc.x)));
    #pragma unroll
    for (int o = 32; o; o >>= 1) {
      p0 += __shfl_xor(p0, o, 64);
      p1 += __shfl_xor(p1, o, 64);
      p2 += __shfl_xor(p2, o, 64);
    }
    if (lane == 0) {
      size_t ro_ = (size_t)(blk * 48 + m) * 3;
      out[ro_ + 0] = 1.0f / (1.0f + expf(-(p0 + B30)));
      out[ro_ + 1] = 1.0f / (1.0f + expf(-(p1 + B31)));
      out[ro_ + 2] = 1.0f / (1.0f + expf(-(p2 + B32)));
    }
  }
}

// ---------------------------------------------------------------------------
extern "C" void kernel_launch(void* const* d_in, const int* in_sizes, int n_in,
                              void* d_out, int out_size, void* d_ws, size_t ws_size,
                              hipStream_t stream) {
  const float* points  = (const float*)d_in[0];
  const float* normals = (const float*)d_in[1];
  const float* fvec    = (const float*)d_in[3];
  const float* parts   = (const float*)d_in[5];
  const float* rays    = (const float*)d_in[6];
  const float* ro      = (const float*)d_in[7];
  const float* W0 = (const float*)d_in[8];
  const float* b0 = (const float*)d_in[9];
  const float* W1 = (const float*)d_in[10];
  const float* b1 = (const float*)d_in[11];
  const float* W2 = (const float*)d_in[12];
  const float* b2 = (const float*)d_in[13];
  const float* W3 = (const float*)d_in[14];
  const float* b3 = (const float*)d_in[15];

  char* ws = (char*)d_ws;
  u16* Xh  = (u16*)(ws);                     // [24576,256] swizzled, 12.58 MB
  u16* Xl  = (u16*)(ws + 12582912);
  u16* w0h = (u16*)(ws + 25165824);          // 262144 B
  u16* w0l = (u16*)(ws + 25427968);
  u16* w1h = (u16*)(ws + 25690112);          // 131072 B
  u16* w1l = (u16*)(ws + 25821184);
  u16* w2h = (u16*)(ws + 25952256);
  u16* w2l = (u16*)(ws + 26083328);
  float* stats = (float*)(ws + 26214400);    // 24576*20*4 = 1.97 MB
  float* spx = (float*)(ws + 28180480);
  float* spy = (float*)(ws + 28196864);
  float* spz = (float*)(ws + 28213248);
  u16* sidx = (u16*)(ws + 28229632);
  u16* cellStart = (u16*)(ws + 28237824);
  float* out = (float*)d_out;

  (void)hipFuncSetAttribute((const void*)fused_mlp,
                            hipFuncAttributeMaxDynamicSharedMemorySize, 81920);

  prep_weights<<<1024, 256, 0, stream>>>(W0, W1, W2, w0h, w0l, w1h, w1l, w2h, w2l);
  grid_build<<<1, 1024, 0, stream>>>(parts, spx, spy, spz, sidx, cellStart);
  query_kernel<<<96, 256, 0, stream>>>(points, normals, rays, ro,
                                       spx, spy, spz, sidx, cellStart, stats);
  posenc_kernel<<<1536, 1024, 0, stream>>>(stats, Xh, Xl);
  fused_mlp<<<512, 256, 81920, stream>>>(Xh, Xl, fvec, w0h, w0l, w1h, w1l, w2h, w2l,
                                         b0, b1, b2, W3, b3, out);
}

// Round 6
// 213.664 us; speedup vs baseline: 1.0241x; 1.0241x over previous
//
#include <hip/hip_runtime.h>

typedef __bf16 bf16x8 __attribute__((ext_vector_type(8)));
typedef float f32x4 __attribute__((ext_vector_type(4)));
typedef unsigned short u16;

__device__ __forceinline__ u16 f2b(float f) {
  unsigned u = __builtin_bit_cast(unsigned, f);
  u = (u + 0x7FFFu + ((u >> 16) & 1u)) >> 16;
  return (u16)u;
}
__device__ __forceinline__ float b2f(u16 h) {
  return __builtin_bit_cast(float, (unsigned)h << 16);
}

// async global->LDS, 16B per lane. dst = wave-uniform base + lane*16.
__device__ __forceinline__ void glds16(const u16* g, u16* l) {
  __builtin_amdgcn_global_load_lds(
      (const __attribute__((address_space(1))) unsigned*)g,
      (__attribute__((address_space(3))) unsigned*)l, 16, 0, 0);
}

// ---------------------------------------------------------------------------
// Swizzled layouts (16B = 8-u16 units, BK=32 K-tiles):
// X [24576,256]: q -> b=q/48, m=q%48; c -> kt=c>>5, g=(c>>3)&3, j=c&7;
//   u = m*4 + (g ^ ((m>>1)&3));  elem off = b*12288 + kt*1536 + u*8 + j
// W [256,K]: n,c -> kt=c>>5, g=(c>>3)&3, j=c&7; u = n*4 + (g^((n>>1)&3));
//   off = kt*8192 + u*8 + j
// H (LDS, 48x256): m,k -> g=k>>3 in [0,32); u = m*32 + (g ^ ((m>>1)&7))
// ---------------------------------------------------------------------------

// ---------------------------------------------------------------------------
// Column decode table: col -> (src scalar idx, freq, kind)
// kind: 0 raw, 1 sin, 2 cos, 3 zero.  enc = src | f<<5 | kind<<9
// ---------------------------------------------------------------------------
struct FT {
  u16 v[256];
  static constexpr u16 enc(int s, int f, int k) {
    return (u16)(s | (f << 5) | (k << 9));
  }
  constexpr void p3(int base, int F, int src) {
    v[base + 0] = enc(src + 0, 0, 0);
    v[base + 1] = enc(src + 1, 0, 0);
    v[base + 2] = enc(src + 2, 0, 0);
    for (int f = 0; f < F; ++f)
      for (int r = 0; r < 6; ++r) {
        int comp = (r < 3) ? r : r - 3;
        v[base + 3 + f * 6 + r] = enc(src + comp, f, (r < 3) ? 1 : 2);
      }
  }
  constexpr void p1(int base, int F, int src) {
    v[base] = enc(src, 0, 0);
    for (int f = 0; f < F; ++f) {
      v[base + 1 + 2 * f] = enc(src, f, 1);
      v[base + 2 + 2 * f] = enc(src, f, 2);
    }
  }
  constexpr FT() : v{} {
    p3(0, 10, 0);     // hit_pos_emb   (q)          [0..62]
    p1(63, 4, 3);     // density_emb                [63..71]
    p3(72, 10, 4);    // smoothed_emb  (sp)         [72..134]
    p3(135, 10, 7);   // var_emb       (var)        [135..197]
    p3(198, 4, 10);   // hit_dir_emb   (ray dir)    [198..224]
    p3(225, 4, 13);   // dirs_emb      (dir)        [225..251]
    v[252] = enc(16, 0, 0);  // normals
    v[253] = enc(17, 0, 0);
    v[254] = enc(18, 0, 0);
    v[255] = enc(0, 0, 3);   // pad col
  }
};
__constant__ FT ftab = FT();

// ---------------------------------------------------------------------------
// Kernel 1: weight prep fp32 -> split bf16 planes, BK=32 swizzled layout.
// W0 [256,511] -> [256,512]: col 255 = 0, cols 256..511 = orig 255..510.
// ---------------------------------------------------------------------------
__global__ __launch_bounds__(256) void prep_weights(
    const float* __restrict__ W0, const float* __restrict__ W1,
    const float* __restrict__ W2,
    u16* __restrict__ w0h, u16* __restrict__ w0l,
    u16* __restrict__ w1h, u16* __restrict__ w1l,
    u16* __restrict__ w2h, u16* __restrict__ w2l)
{
  int i = blockIdx.x * 256 + threadIdx.x;   // 0 .. 262143
  float v; u16 *ph, *pl; int n, c;
  if (i < 131072) {
    n = i >> 9; c = i & 511;
    v = (c < 255) ? W0[n * 511 + c] : ((c == 255) ? 0.0f : W0[n * 511 + (c - 1)]);
    ph = w0h; pl = w0l;
  } else if (i < 196608) {
    int j = i - 131072; n = j >> 8; c = j & 255; v = W1[j]; ph = w1h; pl = w1l;
  } else {
    int j = i - 196608; n = j >> 8; c = j & 255; v = W2[j]; ph = w2h; pl = w2l;
  }
  int kt = c >> 5, g = (c >> 3) & 3, jj = c & 7;
  int u = n * 4 + (g ^ ((n >> 1) & 3));
  int off = kt * 8192 + u * 8 + jj;
  u16 h = f2b(v);
  ph[off] = h;
  pl[off] = f2b(v - b2f(h));
}

// ---------------------------------------------------------------------------
// Kernel 2: ball query + features -> swizzled X planes [24576,256].
// 1 wave/query, 16 queries/block. Lane i scans particles {j*64+i};
// first-16-by-index preserved via ballot prefix. (Proven 69-75us structure.)
// ---------------------------------------------------------------------------
__global__ __launch_bounds__(1024) void feat_kernel(
    const float* __restrict__ points, const float* __restrict__ normals,
    const float* __restrict__ parts, const float* __restrict__ rays,
    const float* __restrict__ ro,
    u16* __restrict__ Xh, u16* __restrict__ Xl)
{
  __shared__ float2 pxy[4096];
  __shared__ float  pzs[4096];
  __shared__ float  sdata[16][20];

  const int tid = threadIdx.x;
  for (int j = tid; j < 4096; j += 1024) {
    pxy[j] = make_float2(parts[3 * j + 0], parts[3 * j + 1]);
    pzs[j] = parts[3 * j + 2];
  }
  __syncthreads();

  const int lane = tid & 63, wv = tid >> 6;
  const int q = blockIdx.x * 16 + wv;
  const float qx = points[3 * q], qy = points[3 * q + 1], qz = points[3 * q + 2];
  const float RQ = 0.1f * 0.1f;

  int nAcc = 0, total = 0;
  float sdx = 0, sdy = 0, sdz = 0;
  float s2x = 0, s2y = 0, s2z = 0;
  float sw = 0, swx = 0, swy = 0, swz = 0;

  for (int jr = 0; jr < 64; ++jr) {
    float2 xy = pxy[jr * 64 + lane];
    float z = pzs[jr * 64 + lane];
    float ex = xy.x - qx, ey = xy.y - qy, ez = z - qz;
    float d2 = __fadd_rn(__fadd_rn(__fmul_rn(ex, ex), __fmul_rn(ey, ey)), __fmul_rn(ez, ez));
    bool hit = d2 < RQ;
    unsigned long long m = __ballot(hit);
    int pos = __builtin_amdgcn_mbcnt_hi((unsigned)(m >> 32),
              __builtin_amdgcn_mbcnt_lo((unsigned)m, 0u));
    if (hit && (total + pos < 16)) {
      nAcc++;
      sdx += ex; sdy += ey; sdz += ez;
      s2x += ex * ex; s2y += ey * ey; s2z += ez * ez;
      float dn = sqrtf(d2);
      float t = dn * 10.0f;
      float w = fmaxf(1.0f - t * t * t, 0.0f);
      sw += w; swx += w * xy.x; swy += w * xy.y; swz += w * z;
    }
    total += __popcll(m);
    if (total >= 16) break;
  }

  #define WRED(x) { _Pragma("unroll") for (int o = 32; o; o >>= 1) x += __shfl_xor(x, o, 64); }
  float fn = (float)nAcc;
  WRED(fn); WRED(sdx); WRED(sdy); WRED(sdz);
  WRED(s2x); WRED(s2y); WRED(s2z);
  WRED(sw); WRED(swx); WRED(swy); WRED(swz);
  #undef WRED

  float tq = sqrtf(qx * qx + qy * qy + qz * qz) * 10.0f;
  float wpad = fmaxf(1.0f - tq * tq * tq, 0.0f);
  float density = sw + (16.0f - fn) * wpad;
  float invd = 1.0f / (density + 1e-12f);
  float spx = swx * invd, spy = swy * invd, spz = swz * invd;

  float invn = 1.0f / (fn + 1e-12f);
  float mx = sdx * invn, my = sdy * invn, mz = sdz * invn;
  float vx = fmaxf((s2x - 2.0f * mx * sdx + fn * mx * mx) * invn, 0.0f);
  float vy = fmaxf((s2y - 2.0f * my * sdy + fn * my * my) * invn, 0.0f);
  float vz = fmaxf((s2z - 2.0f * mz * sdz + fn * mz * mz) * invn, 0.0f);

  float dxx = spx - ro[0], dyy = spy - ro[1], dzz = spz - ro[2];
  float il = 1.0f / sqrtf(dxx * dxx + dyy * dyy + dzz * dzz);

  if (lane == 0) {
    float* s = sdata[wv];
    s[0] = qx; s[1] = qy; s[2] = qz; s[3] = density;
    s[4] = spx; s[5] = spy; s[6] = spz;
    s[7] = vx; s[8] = vy; s[9] = vz;
    int r = q / 48;
    s[10] = rays[6 * r + 3]; s[11] = rays[6 * r + 4]; s[12] = rays[6 * r + 5];
    s[13] = dxx * il; s[14] = dyy * il; s[15] = dzz * il;
    s[16] = normals[3 * q]; s[17] = normals[3 * q + 1]; s[18] = normals[3 * q + 2];
  }
  __syncthreads();

  const int b = q / 48, m96 = q % 48;
  const size_t base = (size_t)b * 12288;
  #pragma unroll
  for (int it = 0; it < 4; ++it) {
    int c = it * 64 + lane;
    int e = ftab.v[c];
    float sv = sdata[wv][e & 31];
    float arg = sv * (float)(1 << ((e >> 5) & 15));
    float sn, cs;
    sincosf(arg, &sn, &cs);
    int kind = e >> 9;
    float val = (kind == 0) ? sv : (kind == 1 ? sn : (kind == 2 ? cs : 0.0f));
    u16 h = f2b(val);
    int kt = c >> 5, g = (c >> 3) & 3, j = c & 7;
    int u = m96 * 4 + (g ^ ((m96 >> 1) & 3));
    size_t off = base + kt * 1536 + u * 8 + j;
    Xh[off] = h;
    Xl[off] = f2b(val - b2f(h));
  }
}

// ---------------------------------------------------------------------------
// Kernel 3: fused 3-layer split-bf16 MFMA MLP + final 256->3 + sigmoid.
// 512 blocks x 256 thr (4 waves, wave tile 48x64), 48 rows/block, 80 KB LDS
// -> 2 blocks/CU. acc += Ah*Bh + Ah*Bl + Al*Bh per fragment pair.
// ---------------------------------------------------------------------------
__global__ __launch_bounds__(256) void fused_mlp(
    const u16* __restrict__ Xh, const u16* __restrict__ Xl,
    const float* __restrict__ fvec,
    const u16* __restrict__ w0h, const u16* __restrict__ w0l,
    const u16* __restrict__ w1h, const u16* __restrict__ w1l,
    const u16* __restrict__ w2h, const u16* __restrict__ w2l,
    const float* __restrict__ b0, const float* __restrict__ b1,
    const float* __restrict__ b2,
    const float* __restrict__ W3, const float* __restrict__ b3,
    float* __restrict__ out)
{
  extern __shared__ char lds[];
  u16* Hh    = (u16*)lds;
  u16* Hl    = (u16*)(lds + 24576);
  u16* Bsh   = (u16*)(lds + 49152);
  u16* Bsl   = (u16*)(lds + 65536);
  u16* Ah_st = (u16*)lds;
  u16* Al_st = (u16*)(lds + 3072);
  float* w3s = (float*)(lds + 49152);

  const int tid = threadIdx.x, lane = tid & 63, wn = tid >> 6;
  const int l15 = lane & 15, l4 = lane >> 4;
  const int blk = blockIdx.x;

  f32x4 acc[3][4];
  #pragma unroll
  for (int i = 0; i < 3; ++i)
    #pragma unroll
    for (int j = 0; j < 4; ++j) acc[i][j] = (f32x4){0, 0, 0, 0};

  const u16* Xht = Xh + (size_t)blk * 12288;
  const u16* Xlt = Xl + (size_t)blk * 12288;

  auto bfrags = [&](bf16x8* bh, bf16x8* bl) {
    #pragma unroll
    for (int j = 0; j < 4; ++j) {
      int n = wn * 64 + j * 16 + l15;
      int u = n * 4 + (l4 ^ ((n >> 1) & 3));
      bh[j] = __builtin_bit_cast(bf16x8, *(const uint4*)(Bsh + u * 8));
      bl[j] = __builtin_bit_cast(bf16x8, *(const uint4*)(Bsl + u * 8));
    }
  };
  auto mfmas = [&](bf16x8* ah, bf16x8* al, bf16x8* bh, bf16x8* bl) {
    #pragma unroll
    for (int i = 0; i < 3; ++i)
      #pragma unroll
      for (int j = 0; j < 4; ++j) {
        acc[i][j] = __builtin_amdgcn_mfma_f32_16x16x32_bf16(ah[i], bh[j], acc[i][j], 0, 0, 0);
        acc[i][j] = __builtin_amdgcn_mfma_f32_16x16x32_bf16(ah[i], bl[j], acc[i][j], 0, 0, 0);
        acc[i][j] = __builtin_amdgcn_mfma_f32_16x16x32_bf16(al[i], bh[j], acc[i][j], 0, 0, 0);
      }
  };
  auto epilogue = [&](const float* bias_) {
    float bv[4];
    #pragma unroll
    for (int j = 0; j < 4; ++j) bv[j] = bias_[wn * 64 + j * 16 + l15];
    #pragma unroll
    for (int i = 0; i < 3; ++i) {
      #pragma unroll
      for (int r = 0; r < 4; ++r) {
        int m = i * 16 + l4 * 4 + r;
        #pragma unroll
        for (int j = 0; j < 4; ++j) {
          int n = wn * 64 + j * 16 + l15;
          float v = fmaxf(acc[i][j][r] + bv[j], 0.0f);
          u16 h = f2b(v);
          int u = m * 32 + ((n >> 3) ^ ((m >> 1) & 7));
          int off = u * 8 + (n & 7);
          Hh[off] = h;
          Hl[off] = f2b(v - b2f(h));
        }
      }
    }
  };

  // ======================= L0: K=512 (8 kt from X, 8 from fvec) ============
  for (int kt = 0; kt < 16; ++kt) {
    if (kt < 8) {
      const u16* s0; u16* d0;
      if (wn < 3) { s0 = Xht + kt * 1536 + wn * 512; d0 = Ah_st + wn * 512; }
      else        { s0 = Xlt + kt * 1536;            d0 = Al_st; }
      glds16(s0 + lane * 8, d0 + lane * 8);
      if (wn < 2)
        glds16(Xlt + kt * 1536 + (wn + 1) * 512 + lane * 8,
               Al_st + (wn + 1) * 512 + lane * 8);
    } else {
      if (tid < 192) {
        int m = tid >> 2, g = tid & 3;
        const float* src = fvec + (size_t)(blk * 48 + m) * 256 + (kt - 8) * 32 + g * 8;
        float4 v0 = ((const float4*)src)[0];
        float4 v1 = ((const float4*)src)[1];
        float vv[8] = {v0.x, v0.y, v0.z, v0.w, v1.x, v1.y, v1.z, v1.w};
        u16 hs[8], ls[8];
        #pragma unroll
        for (int s = 0; s < 8; ++s) {
          hs[s] = f2b(vv[s]);
          ls[s] = f2b(vv[s] - b2f(hs[s]));
        }
        int u = m * 4 + (g ^ ((m >> 1) & 3));
        *(uint4*)(Ah_st + u * 8) = *(uint4*)hs;
        *(uint4*)(Al_st + u * 8) = *(uint4*)ls;
      }
    }
    #pragma unroll
    for (int s = 0; s < 8; ++s) {
      int ch = wn + s * 4;
      const u16* bs = (ch < 16) ? (w0h + kt * 8192 + ch * 512)
                                : (w0l + kt * 8192 + (ch - 16) * 512);
      u16* bd = (ch < 16) ? (Bsh + ch * 512) : (Bsl + (ch - 16) * 512);
      glds16(bs + lane * 8, bd + lane * 8);
    }
    __syncthreads();
    bf16x8 ah[3], al[3], bh[4], bl[4];
    #pragma unroll
    for (int i = 0; i < 3; ++i) {
      int m = i * 16 + l15;
      int u = m * 4 + (l4 ^ ((m >> 1) & 3));
      ah[i] = __builtin_bit_cast(bf16x8, *(const uint4*)(Ah_st + u * 8));
      al[i] = __builtin_bit_cast(bf16x8, *(const uint4*)(Al_st + u * 8));
    }
    bfrags(bh, bl);
    mfmas(ah, al, bh, bl);
    __syncthreads();
  }
  epilogue(b0);
  __syncthreads();

  // ======================= L1, L2: K=256, A from H =========================
  #pragma unroll 1
  for (int layer = 0; layer < 2; ++layer) {
    const u16* wh_ = layer ? w2h : w1h;
    const u16* wl_ = layer ? w2l : w1l;
    #pragma unroll
    for (int i = 0; i < 3; ++i)
      #pragma unroll
      for (int j = 0; j < 4; ++j) acc[i][j] = (f32x4){0, 0, 0, 0};

    for (int kt = 0; kt < 8; ++kt) {
      #pragma unroll
      for (int s = 0; s < 8; ++s) {
        int ch = wn + s * 4;
        const u16* bs = (ch < 16) ? (wh_ + kt * 8192 + ch * 512)
                                  : (wl_ + kt * 8192 + (ch - 16) * 512);
        u16* bd = (ch < 16) ? (Bsh + ch * 512) : (Bsl + (ch - 16) * 512);
        glds16(bs + lane * 8, bd + lane * 8);
      }
      __syncthreads();
      bf16x8 ah[3], al[3], bh[4], bl[4];
      #pragma unroll
      for (int i = 0; i < 3; ++i) {
        int m = i * 16 + l15;
        int g = kt * 4 + l4;
        int u = m * 32 + (g ^ ((m >> 1) & 7));
        ah[i] = __builtin_bit_cast(bf16x8, *(const uint4*)(Hh + u * 8));
        al[i] = __builtin_bit_cast(bf16x8, *(const uint4*)(Hl + u * 8));
      }
      bfrags(bh, bl);
      mfmas(ah, al, bh, bl);
      __syncthreads();
    }
    epilogue(layer ? b2 : b1);
    __syncthreads();
  }

  // ======================= final: 256 -> 3 + sigmoid =======================
  for (int i = tid; i < 768; i += 256) w3s[i] = W3[i];
  __syncthreads();

  const float B30 = b3[0], B31 = b3[1], B32 = b3[2];
  #pragma unroll 1
  for (int rr = 0; rr < 12; ++rr) {
    int m = wn * 12 + rr;
    int g = lane >> 1, j0 = (lane & 1) * 4;
    int u = m * 32 + (g ^ ((m >> 1) & 7));
    uint2 ph_ = *(const uint2*)(Hh + u * 8 + j0);
    uint2 pl_ = *(const uint2*)(Hl + u * 8 + j0);
    float h0 = b2f((u16)(ph_.x & 0xffff)) + b2f((u16)(pl_.x & 0xffff));
    float h1 = b2f((u16)(ph_.x >> 16))    + b2f((u16)(pl_.x >> 16));
    float h2 = b2f((u16)(ph_.y & 0xffff)) + b2f((u16)(pl_.y & 0xffff));
    float h3 = b2f((u16)(ph_.y >> 16))    + b2f((u16)(pl_.y >> 16));
    int kc = lane * 4;
    float4 wa = *(const float4*)(w3s + kc);
    float4 wb = *(const float4*)(w3s + 256 + kc);
    float4 wc = *(const float4*)(w3s + 512 + kc);
    float p0 = fmaf(h3, wa.w, fmaf(h2, wa.z, fmaf(h1, wa.y, h0 * wa.x)));
    float p1 = fmaf(h3, wb.w, fmaf(h2, wb.z, fmaf(h1, wb.y, h0 * wb.x)));
    float p2 = fmaf(h3, wc.w, fmaf(h2, wc.z, fmaf(h1, wc.y, h0 * wc.x)));
    #pragma unroll
    for (int o = 32; o; o >>= 1) {
      p0 += __shfl_xor(p0, o, 64);
      p1 += __shfl_xor(p1, o, 64);
      p2 += __shfl_xor(p2, o, 64);
    }
    if (lane == 0) {
      size_t ro_ = (size_t)(blk * 48 + m) * 3;
      out[ro_ + 0] = 1.0f / (1.0f + expf(-(p0 + B30)));
      out[ro_ + 1] = 1.0f / (1.0f + expf(-(p1 + B31)));
      out[ro_ + 2] = 1.0f / (1.0f + expf(-(p2 + B32)));
    }
  }
}

// ---------------------------------------------------------------------------
extern "C" void kernel_launch(void* const* d_in, const int* in_sizes, int n_in,
                              void* d_out, int out_size, void* d_ws, size_t ws_size,
                              hipStream_t stream) {
  const float* points  = (const float*)d_in[0];
  const float* normals = (const float*)d_in[1];
  const float* fvec    = (const float*)d_in[3];
  const float* parts   = (const float*)d_in[5];
  const float* rays    = (const float*)d_in[6];
  const float* ro      = (const float*)d_in[7];
  const float* W0 = (const float*)d_in[8];
  const float* b0 = (const float*)d_in[9];
  const float* W1 = (const float*)d_in[10];
  const float* b1 = (const float*)d_in[11];
  const float* W2 = (const float*)d_in[12];
  const float* b2 = (const float*)d_in[13];
  const float* W3 = (const float*)d_in[14];
  const float* b3 = (const float*)d_in[15];

  char* ws = (char*)d_ws;
  u16* Xh  = (u16*)(ws);                     // [24576,256] swizzled, 12.58 MB
  u16* Xl  = (u16*)(ws + 12582912);
  u16* w0h = (u16*)(ws + 25165824);          // 262144 B
  u16* w0l = (u16*)(ws + 25427968);
  u16* w1h = (u16*)(ws + 25690112);          // 131072 B
  u16* w1l = (u16*)(ws + 25821184);
  u16* w2h = (u16*)(ws + 25952256);
  u16* w2l = (u16*)(ws + 26083328);
  float* out = (float*)d_out;

  (void)hipFuncSetAttribute((const void*)fused_mlp,
                            hipFuncAttributeMaxDynamicSharedMemorySize, 81920);

  prep_weights<<<1024, 256, 0, stream>>>(W0, W1, W2, w0h, w0l, w1h, w1l, w2h, w2l);
  feat_kernel<<<1536, 1024, 0, stream>>>(points, normals, parts, rays, ro, Xh, Xl);
  fused_mlp<<<512, 256, 81920, stream>>>(Xh, Xl, fvec, w0h, w0l, w1h, w1l, w2h, w2l,
                                         b0, b1, b2, W3, b3, out);
}